// Round 2
// baseline (725.567 us; speedup 1.0000x reference)
//
#include <hip/hip_runtime.h>
#include <hip/hip_bf16.h>

typedef __bf16 bf16x8 __attribute__((ext_vector_type(8)));
typedef float f32x4 __attribute__((ext_vector_type(4)));

#define S_LEN 2048
#define BATCH 32
#define DIM   1024          // ENC_DIM = DEC_DIM
#define FAN   (2*DIM)

// round-to-nearest-even f32 -> bf16 (inputs are never NaN)
__device__ __forceinline__ unsigned short f2bf(float f) {
    union { float f; unsigned u; } x; x.f = f;
    unsigned r = x.u + 0x7FFFu + ((x.u >> 16) & 1u);
    return (unsigned short)(r >> 16);
}

__device__ __forceinline__ float fast_tanh(float x) {
    float e = __expf(2.0f * x);
    return 1.0f - 2.0f / (e + 1.0f);
}

// XOR chunk swizzle: row-major [128 rows][128 bytes], 16B chunks spread across banks
__device__ __forceinline__ int swz(int row, int col) {   // col in bytes
    return row * 128 + (col ^ ((row & 7) << 4));
}

// hw[b][d] = dot(hidden[b,:], attn_w[d, 0:1024]) + attn_b[d]   (fp32 exact)
__global__ __launch_bounds__(256) void k_hw(const float* __restrict__ hidden,
                                            const float* __restrict__ attn_w,
                                            const float* __restrict__ attn_b,
                                            float* __restrict__ hw) {
    int t = blockIdx.x * 256 + threadIdx.x;   // 32768 = 1024 d * 32 b
    int d = t >> 5, b = t & 31;
    const float4* wrow = (const float4*)(attn_w + (size_t)d * FAN);
    const float4* hrow = (const float4*)(hidden + (size_t)b * DIM);
    float acc = 0.f;
    #pragma unroll 4
    for (int k = 0; k < DIM / 4; ++k) {
        float4 w = wrow[k], h = hrow[k];
        acc += w.x*h.x + w.y*h.y + w.z*h.z + w.w*h.w;
    }
    hw[(size_t)b * DIM + d] = acc + attn_b[d];
}

// W2bf[n][k] = bf16(attn_w[n, 1024+k])
__global__ __launch_bounds__(256) void k_w2bf(const float* __restrict__ attn_w,
                                              unsigned short* __restrict__ w2bf) {
    int t = blockIdx.x * 256 + threadIdx.x;   // 262144 threads x 4 elems
    int n  = t >> 8;
    int k4 = (t & 255) * 4;
    float4 w = *(const float4*)(attn_w + (size_t)n * FAN + DIM + k4);
    ushort4 o;
    o.x = f2bf(w.x); o.y = f2bf(w.y); o.z = f2bf(w.z); o.w = f2bf(w.w);
    *(ushort4*)(w2bf + (size_t)n * DIM + k4) = o;
}

// Main fused GEMM: C[m][n] = enc_row(m) . W2_row(n), then
// partial[m, slot] = sum_{n in wave-slice} v[n]*tanh(C[m][n] + hw[m&31][n])
__global__ __launch_bounds__(256, 4) void k_main(const float* __restrict__ enc,
                                                 const unsigned short* __restrict__ w2bf,
                                                 const float* __restrict__ hw,
                                                 const float* __restrict__ vvec,
                                                 float* __restrict__ partials) {
    __shared__ unsigned char Asm[128 * 128];   // [128 rows][64 bf16], XOR-swizzled
    __shared__ unsigned char Bsm[128 * 128];
    const int tid = threadIdx.x;

    // XCD-aware remap: dispatch round-robins blockIdx over 8 XCDs. Make the 8
    // blocks sharing an A-tile (same mb, nb=0..7) consecutive on ONE XCD so
    // enc is fetched from HBM once and w2bf stays L2-resident per XCD.
    const int x  = blockIdx.x & 7;        // XCD id
    const int i  = blockIdx.x >> 3;       // local sequence on XCD x
    const int nb = i & 7;                 // 8 N-blocks
    const int mb = ((i >> 3) << 3) | x;   // 512 M-blocks, bijective
    const int m0 = mb * 128, n0 = nb * 128;
    const int lane = tid & 63, wid = tid >> 6;
    const int wr = wid >> 1, wc = wid & 1;

    // A staging map: 8 passes of 16 rows; 16 float4 per row
    const int ar = tid >> 4, ac = tid & 15;
    const float* aptr = enc + (size_t)(m0 + ar) * DIM + ac * 4;
    // B staging map: 4 passes of 32 rows; 8 x uint4(16B=8 bf16) per row
    const int br = tid >> 3, bc = tid & 7;
    const unsigned short* bptr = w2bf + (size_t)(n0 + br) * DIM + bc * 8;

    f32x4 acc[4][4];
    #pragma unroll
    for (int i2 = 0; i2 < 4; ++i2)
        #pragma unroll
        for (int j = 0; j < 4; ++j) acc[i2][j] = (f32x4){0.f, 0.f, 0.f, 0.f};

    float4 areg[8];
    uint4  breg[4];
    #pragma unroll
    for (int p = 0; p < 8; ++p) areg[p] = *(const float4*)(aptr + p * 16 * DIM);
    #pragma unroll
    for (int p = 0; p < 4; ++p) breg[p] = *(const uint4*)(bptr + p * 32 * DIM);

    #pragma unroll 1
    for (int t = 0; t < 16; ++t) {
        __syncthreads();   // previous tile's LDS reads done
        #pragma unroll
        for (int p = 0; p < 8; ++p) {
            ushort4 c;
            c.x = f2bf(areg[p].x); c.y = f2bf(areg[p].y);
            c.z = f2bf(areg[p].z); c.w = f2bf(areg[p].w);
            *(ushort4*)(&Asm[swz(ar + p * 16, ac * 8)]) = c;
        }
        #pragma unroll
        for (int p = 0; p < 4; ++p)
            *(uint4*)(&Bsm[swz(br + p * 32, bc * 16)]) = breg[p];
        if (t + 1 < 16) {                 // prefetch next K-tile (overlaps MFMA)
            const int ko = (t + 1) * 64;
            #pragma unroll
            for (int p = 0; p < 8; ++p) areg[p] = *(const float4*)(aptr + ko + p * 16 * DIM);
            #pragma unroll
            for (int p = 0; p < 4; ++p) breg[p] = *(const uint4*)(bptr + ko + p * 32 * DIM);
        }
        __syncthreads();   // LDS writes visible

        const int lrow = lane & 15;
        const int kbyte0 = (lane >> 4) * 16;            // 8 bf16 group within K=32 slice
        #pragma unroll
        for (int kk = 0; kk < 2; ++kk) {
            const int kbyte = kbyte0 + kk * 64;
            bf16x8 af[4], bf[4];
            #pragma unroll
            for (int i2 = 0; i2 < 4; ++i2)
                af[i2] = *(const bf16x8*)(&Asm[swz(wr * 64 + i2 * 16 + lrow, kbyte)]);
            #pragma unroll
            for (int j = 0; j < 4; ++j)
                bf[j] = *(const bf16x8*)(&Bsm[swz(wc * 64 + j * 16 + lrow, kbyte)]);
            #pragma unroll
            for (int i2 = 0; i2 < 4; ++i2)
                #pragma unroll
                for (int j = 0; j < 4; ++j)
                    acc[i2][j] = __builtin_amdgcn_mfma_f32_16x16x32_bf16(af[i2], bf[j], acc[i2][j], 0, 0, 0);
        }
    }

    // fused epilogue: tanh + v-weighted reduce over this wave's 64 n-columns
    const int colg = lane & 15, rowg = lane >> 4;
    #pragma unroll
    for (int i2 = 0; i2 < 4; ++i2) {
        #pragma unroll
        for (int r = 0; r < 4; ++r) {
            const int m = m0 + wr * 64 + i2 * 16 + rowg * 4 + r;
            const float* hwrow = hw + (size_t)(m & 31) * DIM + n0 + wc * 64;
            const float* vrow  = vvec + n0 + wc * 64;
            float sumv = 0.f;
            #pragma unroll
            for (int j = 0; j < 4; ++j) {
                const int nl = j * 16 + colg;
                float pre = acc[i2][j][r] + hwrow[nl];
                sumv += vrow[nl] * fast_tanh(pre);
            }
            sumv += __shfl_xor(sumv, 1);
            sumv += __shfl_xor(sumv, 2);
            sumv += __shfl_xor(sumv, 4);
            sumv += __shfl_xor(sumv, 8);
            if (colg == 0) partials[(size_t)m * 16 + nb * 2 + wc] = sumv;
        }
    }
}

// per-batch softmax over s (sums the 16 partials per (s,b) first)
__global__ __launch_bounds__(256) void k_softmax(const float* __restrict__ partials,
                                                 float* __restrict__ out) {
    const int b = blockIdx.x;      // 32
    const int tid = threadIdx.x;   // 256, each handles 8 s-values
    __shared__ float redm[4], reds[4];
    float loc[8];
    float mx = -1e30f;
    #pragma unroll
    for (int i = 0; i < 8; ++i) {
        const int s = tid + i * 256;
        const float4* p = (const float4*)(partials + ((size_t)s * 32 + b) * 16);
        float4 p0 = p[0], p1 = p[1], p2 = p[2], p3 = p[3];
        float v = ((p0.x + p0.y) + (p0.z + p0.w)) + ((p1.x + p1.y) + (p1.z + p1.w))
                + ((p2.x + p2.y) + (p2.z + p2.w)) + ((p3.x + p3.y) + (p3.z + p3.w));
        loc[i] = v; mx = fmaxf(mx, v);
    }
    #pragma unroll
    for (int o = 32; o; o >>= 1) mx = fmaxf(mx, __shfl_xor(mx, o));
    const int wid2 = tid >> 6, lane = tid & 63;
    if (lane == 0) redm[wid2] = mx;
    __syncthreads();
    mx = fmaxf(fmaxf(redm[0], redm[1]), fmaxf(redm[2], redm[3]));
    float sum = 0.f;
    #pragma unroll
    for (int i = 0; i < 8; ++i) { float e = __expf(loc[i] - mx); loc[i] = e; sum += e; }
    #pragma unroll
    for (int o = 32; o; o >>= 1) sum += __shfl_xor(sum, o);
    if (lane == 0) reds[wid2] = sum;
    __syncthreads();
    sum = (reds[0] + reds[1]) + (reds[2] + reds[3]);
    const float rs = 1.0f / sum;
    #pragma unroll
    for (int i = 0; i < 8; ++i) out[(size_t)b * S_LEN + tid + i * 256] = loc[i] * rs;
}

extern "C" void kernel_launch(void* const* d_in, const int* in_sizes, int n_in,
                              void* d_out, int out_size, void* d_ws, size_t ws_size,
                              hipStream_t stream) {
    const float* hidden = (const float*)d_in[0];
    const float* enc    = (const float*)d_in[1];
    const float* attn_w = (const float*)d_in[2];
    const float* attn_b = (const float*)d_in[3];
    const float* v      = (const float*)d_in[4];
    float* out = (float*)d_out;

    char* ws = (char*)d_ws;
    float*          hw       = (float*)ws;                            // 128 KiB
    unsigned short* w2bf     = (unsigned short*)(ws + (128u << 10));  // 2 MiB
    float*          partials = (float*)(ws + (128u << 10) + (2u << 20)); // 4 MiB

    hipLaunchKernelGGL(k_hw,      dim3(128),  dim3(256), 0, stream, hidden, attn_w, attn_b, hw);
    hipLaunchKernelGGL(k_w2bf,    dim3(1024), dim3(256), 0, stream, attn_w, w2bf);
    hipLaunchKernelGGL(k_main,    dim3(4096), dim3(256), 0, stream, enc, w2bf, hw, v, partials);
    hipLaunchKernelGGL(k_softmax, dim3(32),   dim3(256), 0, stream, partials, out);
}

// Round 3
// 314.401 us; speedup vs baseline: 2.3078x; 2.3078x over previous
//
#include <hip/hip_runtime.h>
#include <hip/hip_bf16.h>

typedef __bf16 bf16x8 __attribute__((ext_vector_type(8)));
typedef float f32x4 __attribute__((ext_vector_type(4)));

#define S_LEN 2048
#define BATCH 32
#define DIM   1024          // ENC_DIM = DEC_DIM
#define FAN   (2*DIM)

// round-to-nearest-even f32 -> bf16 (inputs are never NaN)
__device__ __forceinline__ unsigned f2bf_r(float f) {   // returns rounded bits, bf16 in [31:16]
    union { float f; unsigned u; } x; x.f = f;
    return x.u + 0x7FFFu + ((x.u >> 16) & 1u);
}
__device__ __forceinline__ unsigned short f2bf(float f) { return (unsigned short)(f2bf_r(f) >> 16); }
__device__ __forceinline__ unsigned packbf(float lo, float hi) {
    return (f2bf_r(lo) >> 16) | (f2bf_r(hi) & 0xFFFF0000u);
}

__device__ __forceinline__ float fast_tanh(float x) {
    float e = __expf(2.0f * x);
    return 1.0f - 2.0f / (e + 1.0f);
}

// XOR chunk swizzle on a [128 rows][128 bytes] LDS tile
__device__ __forceinline__ int swz(int row, int col) {   // col in bytes
    return row * 128 + (col ^ ((row & 7) << 4));
}

// async 16B global->LDS (LDS dest = wave-uniform base + lane*16)
__device__ __forceinline__ void gload16(const void* g, void* l) {
    __builtin_amdgcn_global_load_lds((const __attribute__((address_space(1))) void*)g,
                                     (__attribute__((address_space(3))) void*)l, 16, 0, 0);
}

// hw[b][d] = dot(hidden[b,:], attn_w[d, 0:1024]) + attn_b[d]   (fp32 exact)
__global__ __launch_bounds__(256) void k_hw(const float* __restrict__ hidden,
                                            const float* __restrict__ attn_w,
                                            const float* __restrict__ attn_b,
                                            float* __restrict__ hw) {
    int t = blockIdx.x * 256 + threadIdx.x;   // 32768 = 1024 d * 32 b
    int d = t >> 5, b = t & 31;
    const float4* wrow = (const float4*)(attn_w + (size_t)d * FAN);
    const float4* hrow = (const float4*)(hidden + (size_t)b * DIM);
    float acc = 0.f;
    #pragma unroll 4
    for (int k = 0; k < DIM / 4; ++k) {
        float4 w = wrow[k], h = hrow[k];
        acc += w.x*h.x + w.y*h.y + w.z*h.z + w.w*h.w;
    }
    hw[(size_t)b * DIM + d] = acc + attn_b[d];
}

// W2bf[n][k] = bf16(attn_w[n, 1024+k])
__global__ __launch_bounds__(256) void k_w2bf(const float* __restrict__ attn_w,
                                              unsigned short* __restrict__ w2bf) {
    int t = blockIdx.x * 256 + threadIdx.x;   // 262144 threads x 4 elems
    int n  = t >> 8;
    int k4 = (t & 255) * 4;
    float4 w = *(const float4*)(attn_w + (size_t)n * FAN + DIM + k4);
    ushort4 o;
    o.x = f2bf(w.x); o.y = f2bf(w.y); o.z = f2bf(w.z); o.w = f2bf(w.w);
    *(ushort4*)(w2bf + (size_t)n * DIM + k4) = o;
}

// Main fused GEMM: C[m][n] = enc_row(m) . W2_row(n), then
// partial[m, slot] = sum_{n in wave-slice} v[n]*tanh(C[m][n] + hw[m&31][n])
__global__ __launch_bounds__(256) void k_main(const float* __restrict__ enc,
                                              const unsigned short* __restrict__ w2bf,
                                              const float* __restrict__ hw,
                                              const float* __restrict__ vvec,
                                              float* __restrict__ partials) {
    __shared__ unsigned char Asm[128 * 128];   // [128 rows][64 bf16], XOR-swizzled content
    __shared__ unsigned char Bsm[128 * 128];
    const int tid = threadIdx.x;

    // XCD-aware bijective remap: the 8 blocks sharing an A-tile (same mb) run
    // consecutively on ONE XCD -> enc fetched from HBM once, then L2 hits.
    const int x  = blockIdx.x & 7;        // XCD id
    const int ii = blockIdx.x >> 3;       // local sequence on XCD x
    const int nb = ii & 7;                // 8 N-blocks
    const int mb = ((ii >> 3) << 3) | x;  // 512 M-blocks, bijective (4096 % 8 == 0)
    const int m0 = mb * 128, n0 = nb * 128;
    const int lane = tid & 63, wid = tid >> 6;
    const int wr = wid >> 1, wc = wid & 1;

    // ---- A staging (reg + cvt): 8 passes of 16 rows; row ar+16p, f32 cols ac*4
    const int ar = tid >> 4, ac = tid & 15;
    const float* aptr = enc + (size_t)(m0 + ar) * DIM + ac * 4;

    // ---- B staging (global_load_lds, linear LDS dest, pre-swizzled source):
    // chunk c = wid*4+p covers rows 8c..8c+7; lane l -> row8 = l>>3,
    // source 16B-slot = (l&7) ^ row8  (equals the read-side XOR since row&7 == row8)
    const int row8 = lane >> 3, colx = (lane & 7) ^ row8;
    const unsigned short* bsrc[4];
    void* bdst[4];
    #pragma unroll
    for (int p = 0; p < 4; ++p) {
        const int c = wid * 4 + p;
        bsrc[p] = w2bf + (size_t)(n0 + 8 * c + row8) * DIM + colx * 8;
        bdst[p] = (void*)&Bsm[c * 1024];
    }

    f32x4 acc[4][4];
    #pragma unroll
    for (int i2 = 0; i2 < 4; ++i2)
        #pragma unroll
        for (int j = 0; j < 4; ++j) acc[i2][j] = (f32x4){0.f, 0.f, 0.f, 0.f};

    float4 areg[8];
    #pragma unroll
    for (int p = 0; p < 8; ++p) areg[p] = *(const float4*)(aptr + p * 16 * DIM);

    #pragma unroll 1
    for (int t = 0; t < 16; ++t) {
        __syncthreads();   // all waves done reading tile t-1 (drains pending areg loads too)
        #pragma unroll
        for (int p = 0; p < 8; ++p) {
            uint4 w;
            w.x = packbf(areg[p].x, areg[p].y);
            w.y = packbf(areg[p].z, areg[p].w);
            // store 8B per thread: two packed pairs
            *(uint2*)(&Asm[swz(ar + p * 16, ac * 8)]) = make_uint2(w.x, w.y);
        }
        #pragma unroll
        for (int p = 0; p < 4; ++p)
            gload16(bsrc[p] + t * 64, bdst[p]);
        __syncthreads();   // vmcnt(0)+lgkmcnt(0): tile t fully in LDS

        if (t + 1 < 16) {  // prefetch next A-tile DURING compute (drained at next barrier1)
            const int ko = (t + 1) * 64;
            #pragma unroll
            for (int p = 0; p < 8; ++p) areg[p] = *(const float4*)(aptr + ko + p * 16 * DIM);
        }

        const int lrow = lane & 15;
        const int kbyte0 = (lane >> 4) * 16;
        #pragma unroll
        for (int kk = 0; kk < 2; ++kk) {
            const int kbyte = kbyte0 + kk * 64;
            bf16x8 af[4], bfr[4];
            #pragma unroll
            for (int i2 = 0; i2 < 4; ++i2)
                af[i2] = *(const bf16x8*)(&Asm[swz(wr * 64 + i2 * 16 + lrow, kbyte)]);
            #pragma unroll
            for (int j = 0; j < 4; ++j)
                bfr[j] = *(const bf16x8*)(&Bsm[swz(wc * 64 + j * 16 + lrow, kbyte)]);
            #pragma unroll
            for (int i2 = 0; i2 < 4; ++i2)
                #pragma unroll
                for (int j = 0; j < 4; ++j)
                    acc[i2][j] = __builtin_amdgcn_mfma_f32_16x16x32_bf16(af[i2], bfr[j], acc[i2][j], 0, 0, 0);
        }
    }

    // fused epilogue: tanh + v-weighted reduce over this wave's 64 n-columns
    const int colg = lane & 15, rowg = lane >> 4;
    #pragma unroll
    for (int i2 = 0; i2 < 4; ++i2) {
        #pragma unroll
        for (int r = 0; r < 4; ++r) {
            const int m = m0 + wr * 64 + i2 * 16 + rowg * 4 + r;
            const float* hwrow = hw + (size_t)(m & 31) * DIM + n0 + wc * 64;
            const float* vrow  = vvec + n0 + wc * 64;
            float sumv = 0.f;
            #pragma unroll
            for (int j = 0; j < 4; ++j) {
                const int nl = j * 16 + colg;
                float pre = acc[i2][j][r] + hwrow[nl];
                sumv += vrow[nl] * fast_tanh(pre);
            }
            sumv += __shfl_xor(sumv, 1);
            sumv += __shfl_xor(sumv, 2);
            sumv += __shfl_xor(sumv, 4);
            sumv += __shfl_xor(sumv, 8);
            if (colg == 0) partials[(size_t)m * 16 + nb * 2 + wc] = sumv;
        }
    }
}

// per-batch softmax over s (sums the 16 partials per (s,b) first)
__global__ __launch_bounds__(256) void k_softmax(const float* __restrict__ partials,
                                                 float* __restrict__ out) {
    const int b = blockIdx.x;      // 32
    const int tid = threadIdx.x;   // 256, each handles 8 s-values
    __shared__ float redm[4], reds[4];
    float loc[8];
    float mx = -1e30f;
    #pragma unroll
    for (int i = 0; i < 8; ++i) {
        const int s = tid + i * 256;
        const float4* p = (const float4*)(partials + ((size_t)s * 32 + b) * 16);
        float4 p0 = p[0], p1 = p[1], p2 = p[2], p3 = p[3];
        float v = ((p0.x + p0.y) + (p0.z + p0.w)) + ((p1.x + p1.y) + (p1.z + p1.w))
                + ((p2.x + p2.y) + (p2.z + p2.w)) + ((p3.x + p3.y) + (p3.z + p3.w));
        loc[i] = v; mx = fmaxf(mx, v);
    }
    #pragma unroll
    for (int o = 32; o; o >>= 1) mx = fmaxf(mx, __shfl_xor(mx, o));
    const int wid2 = tid >> 6, lane = tid & 63;
    if (lane == 0) redm[wid2] = mx;
    __syncthreads();
    mx = fmaxf(fmaxf(redm[0], redm[1]), fmaxf(redm[2], redm[3]));
    float sum = 0.f;
    #pragma unroll
    for (int i = 0; i < 8; ++i) { float e = __expf(loc[i] - mx); loc[i] = e; sum += e; }
    #pragma unroll
    for (int o = 32; o; o >>= 1) sum += __shfl_xor(sum, o);
    if (lane == 0) reds[wid2] = sum;
    __syncthreads();
    sum = (reds[0] + reds[1]) + (reds[2] + reds[3]);
    const float rs = 1.0f / sum;
    #pragma unroll
    for (int i = 0; i < 8; ++i) out[(size_t)b * S_LEN + tid + i * 256] = loc[i] * rs;
}

extern "C" void kernel_launch(void* const* d_in, const int* in_sizes, int n_in,
                              void* d_out, int out_size, void* d_ws, size_t ws_size,
                              hipStream_t stream) {
    const float* hidden = (const float*)d_in[0];
    const float* enc    = (const float*)d_in[1];
    const float* attn_w = (const float*)d_in[2];
    const float* attn_b = (const float*)d_in[3];
    const float* v      = (const float*)d_in[4];
    float* out = (float*)d_out;

    char* ws = (char*)d_ws;
    float*          hw       = (float*)ws;                            // 128 KiB
    unsigned short* w2bf     = (unsigned short*)(ws + (128u << 10));  // 2 MiB
    float*          partials = (float*)(ws + (128u << 10) + (2u << 20)); // 4 MiB

    hipLaunchKernelGGL(k_hw,      dim3(128),  dim3(256), 0, stream, hidden, attn_w, attn_b, hw);
    hipLaunchKernelGGL(k_w2bf,    dim3(1024), dim3(256), 0, stream, attn_w, w2bf);
    hipLaunchKernelGGL(k_main,    dim3(4096), dim3(256), 0, stream, enc, w2bf, hw, v, partials);
    hipLaunchKernelGGL(k_softmax, dim3(32),   dim3(256), 0, stream, partials, out);
}